// Round 11
// baseline (803.794 us; speedup 1.0000x reference)
//
#include <hip/hip_runtime.h>

typedef unsigned short u16;
typedef __attribute__((ext_vector_type(8))) short s8;
typedef __attribute__((ext_vector_type(4))) short s4;
typedef __attribute__((ext_vector_type(4))) float f4;

#define N_TRAJ 4096
#define TSTEPS 128
#define LATD   64
#define INPD   128
#define MROWS  8      // real trajectories per block; tile rows 8-15 are clones

// bias offsets (floats)
#define OB1 0
#define OB2 128
#define UB1 192
#define UB2 320
#define RB1 384
#define RB2 512
#define NB1 576
#define NB2 704
#define TB1 832
#define TB2 960
#define DTS 1088
#define NBIAS 1216

// packed weight offsets (elements)
#define OFF_UG1 0
#define OFF_RG1 32768
#define OFF_NS1 65536
#define OFF_OD1 98304
#define OFF_UG2 106496
#define OFF_RG2 114688
#define OFF_NS2 122880
#define OFF_OD2 139264
#define OFF_TZ1 147456
#define OFF_TZ2 163840
#define PACK_ELEMS 180224

#define SYO 68   // f32 state stride

__device__ u16 g_pack[PACK_ELEMS];
__device__ float g_bias[NBIAS];

__device__ __forceinline__ float b2f(u16 u) {
    union { unsigned int i; float f; } v; v.i = ((unsigned int)u) << 16; return v.f;
}
__device__ __forceinline__ u16 f2b(float f) {
    unsigned int x = __float_as_uint(f);
    unsigned int r = (x + 0x7FFFu + ((x >> 16) & 1u)) >> 16;
    return (u16)r;
}
__device__ __forceinline__ unsigned int cvtpk(float lo, float hi) {
    unsigned int r;
    asm("v_cvt_pk_bf16_f32 %0, %1, %2" : "=v"(r) : "v"(lo), "v"(hi));
    return r;
}
__device__ __forceinline__ int is_f32(const void* tps) {
    return (*(const unsigned int*)tps) == 0u;
}
__device__ __forceinline__ float rdany(const void* a, int i, int isf32) {
    return isf32 ? ((const float*)a)[i] : b2f(((const u16*)a)[i]);
}
__device__ __forceinline__ float sigm(float x) {
    x = fminf(fmaxf(x, -30.f), 30.f);
    float e = __expf(-x);
    return __builtin_amdgcn_rcpf(1.f + e);
}
__device__ __forceinline__ float tanh_(float x) {
    x = fminf(fmaxf(x, -15.f), 15.f);
    float e = __expf(-2.f * x);
    return (1.f - e) * __builtin_amdgcn_rcpf(1.f + e);
}

// activation fragment read (MFMA B operand): lane l -> traj = l&15, k = ks*32 + (l>>4)*8 + i
__device__ __forceinline__ s8 aread(const u16* buf, int lane, int ks) {
    int row = lane & 15;
    int b = (ks << 6) + ((lane >> 4) << 4);
    int off = (row << 8) + (b ^ ((row & 7) << 4));
    return *(const s8*)((const char*)buf + off);
}
__device__ __forceinline__ void hwrite4(u16* buf, int traj, int ncol0, float a, float b, float c, float d) {
    int off = (traj << 8) + ((ncol0 << 1) ^ ((traj & 7) << 4));
    uint2 v;
    v.x = cvtpk(a, b);
    v.y = cvtpk(c, d);
    *(uint2*)((char*)buf + off) = v;
}
__device__ __forceinline__ s4 sread4(const u16* buf, int traj, int col0) {
    int off = (traj << 8) + ((col0 << 1) ^ ((traj & 7) << 4));
    return *(const s4*)((const char*)buf + off);
}
__device__ __forceinline__ s4 load_x4(const void* data, size_t elemIdx, int isf32) {
    s4 r;
    if (isf32) {
        f4 v = *(const f4*)((const float*)data + elemIdx);
#pragma unroll
        for (int j = 0; j < 4; ++j) r[j] = (short)f2b(v[j]);
    } else {
        r = *(const s4*)((const u16*)data + elemIdx);
    }
    return r;
}

struct PackP {
    const void* src[10];
    const void* tps;
    int Kr[10], Nr[10], KS[10], sz[10];
};

__global__ __launch_bounds__(256) void repack_kernel(PackP p) {
    int gid = blockIdx.x * 256 + threadIdx.x;
    if (gid >= PACK_ELEMS) return;
    int isf32 = is_f32(p.tps);
    int idx = gid, m = 0, base = 0;
    while (m < 10 && idx >= p.sz[m]) { idx -= p.sz[m]; base += p.sz[m]; ++m; }
    if (m >= 10) return;
    int i = idx & 7;
    int l = (idx >> 3) & 63;
    int rest = idx >> 9;
    int ks = rest % p.KS[m];
    int nt = rest / p.KS[m];
    int k = ks * 32 + ((l >> 4) << 3) + i;
    int n = nt * 16 + (l & 15);
    u16 v = 0;
    if (k < p.Kr[m] && n < p.Nr[m]) v = f2b(rdany(p.src[m], k * p.Nr[m] + n, isf32));
    g_pack[base + idx] = v;
}

struct PrepP {
    const void *tps, *ob1, *ob2, *ub1, *ub2, *rb1, *rb2, *nb1, *nb2, *tb1, *tb2;
};

__global__ __launch_bounds__(256) void prep_bias(PrepP p) {
    int isf32 = is_f32(p.tps);
    int tid = threadIdx.x;
    for (int i = tid; i < 128; i += 256) {
        g_bias[OB1 + i] = (i < 100) ? rdany(p.ob1, i, isf32) : 0.f;
        g_bias[UB1 + i] = (i < 100) ? rdany(p.ub1, i, isf32) : 0.f;
        g_bias[RB1 + i] = (i < 100) ? rdany(p.rb1, i, isf32) : 0.f;
        g_bias[NB1 + i] = (i < 100) ? rdany(p.nb1, i, isf32) : 0.f;
        g_bias[TB1 + i] = (i < 100) ? rdany(p.tb1, i, isf32) : 0.f;
        g_bias[NB2 + i] = rdany(p.nb2, i, isf32);
        g_bias[TB2 + i] = rdany(p.tb2, i, isf32);
        g_bias[DTS + i] = (i == 0) ? -0.01f
                                   : (rdany(p.tps, 127 - i, isf32) - rdany(p.tps, 128 - i, isf32));
    }
    for (int i = tid; i < 64; i += 256) {
        g_bias[OB2 + i] = rdany(p.ob2, i, isf32);
        g_bias[UB2 + i] = rdany(p.ub2, i, isf32);
        g_bias[RB2 + i] = rdany(p.rb2, i, isf32);
    }
}

struct MainP {
    const void *data, *tps;
    void* out;
};

#define WLOAD(off, KSn, nt, ks) (*(const s8*)(pk + (off) + (((((nt) * (KSn)) + (ks)) << 6) + lane) * 8))
// TRANSPOSED: A = weight fragment, B = activation fragment -> C[ncol][traj]
#define MFMA(wf, af, c) __builtin_amdgcn_mfma_f32_16x16x32_bf16((wf), (af), (c), 0, 0, 0)

__global__ __launch_bounds__(512, 2) void enc_main(MainP p) {
    __shared__ u16 s_x[2][2048];   // [16][128] bf16 swizzled, double buffered
    __shared__ u16 s_yc[2048];     // [y | s]
    __shared__ u16 s_yc2[2048];    // [y_ode*r | s*r]
    __shared__ u16 s_hA[2048];     // h buffer (hode/hu/hns)
    __shared__ u16 s_hB[2048];     // hr
    __shared__ float s_yo[16 * SYO];
    __shared__ float s_u[16 * SYO];
    __shared__ float s_b[NBIAS];

    int tid = threadIdx.x, lane = tid & 63, w = tid >> 6;   // w = 0..7
    int btraj = blockIdx.x * MROWS;
    const u16* pk = g_pack;
    int isf32 = is_f32(p.tps);

    for (int i = tid; i < NBIAS; i += 512) s_b[i] = g_bias[i];
    for (int i = tid; i < 2048; i += 512) s_yc[i] = 0;

    // persistent per-wave layer-1 weight fragments (nt = w)
    s8 wl1u[8], wl1r[8], wl1n[8];
    s8 wod1[2];
#pragma unroll
    for (int ks = 0; ks < 8; ++ks) {
        wl1u[ks] = WLOAD(OFF_UG1, 8, w, ks);
        wl1r[ks] = WLOAD(OFF_RG1, 8, w, ks);
        wl1n[ks] = WLOAD(OFF_NS1, 8, w, ks);
    }
    wod1[0] = WLOAD(OFF_OD1, 2, w, 0);
    wod1[1] = WLOAD(OFF_OD1, 2, w, 1);

    f4 ymu_r = {0.f, 0.f, 0.f, 0.f};
    f4 s_r = {0.f, 0.f, 0.f, 0.f};
    f4 yo_r = {0.f, 0.f, 0.f, 0.f};
    f4 u_r = {0.f, 0.f, 0.f, 0.f};

    // x prefetch: rows 8-15 duplicate rows 0-7 (same global addresses -> L1 hits)
    int xrow = tid >> 5, xk = tid & 31;
    int xsrc = xrow & (MROWS - 1);
    int xoff = (xrow << 8) + ((xk << 3) ^ ((xrow & 7) << 4));
    {
        s4 xr = load_x4(p.data, ((size_t)(btraj + xsrc) * TSTEPS + 127) * INPD + (xk << 2), isf32);
        *(s4*)((char*)s_x[0] + xoff) = xr;
    }
    __syncthreads();

    const f4 zero4 = {0.f, 0.f, 0.f, 0.f};
    int traj = lane & 15;
    int nbase = (w << 4) + ((lane >> 4) << 2);   // first of 4 owned output cols (0..127)

    for (int it = 0; it < TSTEPS; ++it) {
        int cur = it & 1;
        float dt = s_b[DTS + it];

        s4 xnext;
        if (it < 127) {
            xnext = load_x4(p.data, ((size_t)(btraj + xsrc) * TSTEPS + (126 - it)) * INPD + (xk << 2), isf32);
        }

        f4 au = zero4, ar = zero4;

        // ---- Phase A: ODE layer 1 + u1/r1 partials over s (ks2,3) and x (ks4-7) ----
        {
            f4 ao = zero4;
            ao = MFMA(wod1[0], aread(s_yc, lane, 0), ao);
            ao = MFMA(wod1[1], aread(s_yc, lane, 1), ao);
#pragma unroll
            for (int ks = 2; ks < 4; ++ks) {
                s8 a = aread(s_yc, lane, ks);
                au = MFMA(wl1u[ks], a, au);
                ar = MFMA(wl1r[ks], a, ar);
            }
#pragma unroll
            for (int ks = 0; ks < 4; ++ks) {
                s8 a = aread(s_x[cur], lane, ks);
                au = MFMA(wl1u[4 + ks], a, au);
                ar = MFMA(wl1r[4 + ks], a, ar);
            }
            f4 b4 = *(const f4*)(s_b + OB1 + nbase);
            hwrite4(s_hA, traj, nbase, tanh_(ao[0] + b4[0]), tanh_(ao[1] + b4[1]),
                    tanh_(ao[2] + b4[2]), tanh_(ao[3] + b4[3]));
        }
        __syncthreads();

        // ---- Phase B: ODE layer 2 -> y_ode (waves 0-3) ----
        if (w < 4) {
            s8 wod2[4];
#pragma unroll
            for (int ks = 0; ks < 4; ++ks) wod2[ks] = WLOAD(OFF_OD2, 4, w, ks);
            f4 ac = zero4;
#pragma unroll
            for (int ks = 0; ks < 4; ++ks) ac = MFMA(wod2[ks], aread(s_hA, lane, ks), ac);
            f4 b4 = *(const f4*)(s_b + OB2 + nbase);
#pragma unroll
            for (int j = 0; j < 4; ++j) yo_r[j] = ymu_r[j] + (ac[j] + b4[j]) * dt;
            *(f4*)(s_yo + traj * SYO + nbase) = yo_r;
            hwrite4(s_yc, traj, nbase, yo_r[0], yo_r[1], yo_r[2], yo_r[3]);
        }
        __syncthreads();

        // ---- Phase C: u1/r1 finish with y_ode part (ks0,1) ----
        {
#pragma unroll
            for (int ks = 0; ks < 2; ++ks) {
                s8 a = aread(s_yc, lane, ks);
                au = MFMA(wl1u[ks], a, au);
                ar = MFMA(wl1r[ks], a, ar);
            }
            f4 bu4 = *(const f4*)(s_b + UB1 + nbase);
            f4 br4 = *(const f4*)(s_b + RB1 + nbase);
            hwrite4(s_hA, traj, nbase, tanh_(au[0] + bu4[0]), tanh_(au[1] + bu4[1]),
                    tanh_(au[2] + bu4[2]), tanh_(au[3] + bu4[3]));
            hwrite4(s_hB, traj, nbase, tanh_(ar[0] + br4[0]), tanh_(ar[1] + br4[1]),
                    tanh_(ar[2] + br4[2]), tanh_(ar[3] + br4[3]));
        }
        __syncthreads();

        // ---- Phase D: ns1 x-part (all) + u2 (waves 0-3) / r2 + build yc2 (waves 4-7) ----
        f4 an = zero4;
        {
#pragma unroll
            for (int ks = 0; ks < 4; ++ks)
                an = MFMA(wl1n[4 + ks], aread(s_x[cur], lane, ks), an);
        }
        if (w < 4) {
            s8 w2[4];
#pragma unroll
            for (int ks = 0; ks < 4; ++ks) w2[ks] = WLOAD(OFF_UG2, 4, w, ks);
            f4 uac = zero4;
#pragma unroll
            for (int ks = 0; ks < 4; ++ks) uac = MFMA(w2[ks], aread(s_hA, lane, ks), uac);
            f4 b4 = *(const f4*)(s_b + UB2 + nbase);
#pragma unroll
            for (int j = 0; j < 4; ++j) u_r[j] = sigm(uac[j] + b4[j]);
            *(f4*)(s_u + traj * SYO + nbase) = u_r;
        } else {
            s8 w2[4];
#pragma unroll
            for (int ks = 0; ks < 4; ++ks) w2[ks] = WLOAD(OFF_RG2, 4, w - 4, ks);
            f4 rac = zero4;
#pragma unroll
            for (int ks = 0; ks < 4; ++ks) rac = MFMA(w2[ks], aread(s_hB, lane, ks), rac);
            int sb = nbase - 64;
            f4 b4 = *(const f4*)(s_b + RB2 + sb);
            f4 yo4 = *(const f4*)(s_yo + traj * SYO + sb);
            f4 rv;
#pragma unroll
            for (int j = 0; j < 4; ++j) rv[j] = sigm(rac[j] + b4[j]);
            hwrite4(s_yc2, traj, sb, yo4[0] * rv[0], yo4[1] * rv[1], yo4[2] * rv[2], yo4[3] * rv[3]);
            hwrite4(s_yc2, traj, nbase, s_r[0] * rv[0], s_r[1] * rv[1], s_r[2] * rv[2], s_r[3] * rv[3]);
        }
        __syncthreads();

        // ---- Phase E: ns layer 1 finish (yc2 part), all waves ----
        {
#pragma unroll
            for (int ks = 0; ks < 4; ++ks) an = MFMA(wl1n[ks], aread(s_yc2, lane, ks), an);
            f4 b4 = *(const f4*)(s_b + NB1 + nbase);
            hwrite4(s_hA, traj, nbase, tanh_(an[0] + b4[0]), tanh_(an[1] + b4[1]),
                    tanh_(an[2] + b4[2]), tanh_(an[3] + b4[3]));
        }
        __syncthreads();

        // ---- Phase F: ns layer 2 + state update, all waves ----
        {
            s8 wn2[4];
#pragma unroll
            for (int ks = 0; ks < 4; ++ks) wn2[ks] = WLOAD(OFF_NS2, 4, w, ks);
            f4 fn = zero4;
#pragma unroll
            for (int ks = 0; ks < 4; ++ks) fn = MFMA(wn2[ks], aread(s_hA, lane, ks), fn);
            if (it < 127) *(s4*)((char*)s_x[cur ^ 1] + xoff) = xnext;

            f4 b4 = *(const f4*)(s_b + NB2 + nbase);
            if (w < 4) {
                s4 mm = sread4(s_x[cur], traj, 64 + nbase);
#pragma unroll
                for (int j = 0; j < 4; ++j) {
                    float nsv = fn[j] + b4[j];
                    float m = b2f((u16)mm[j]);
                    float mg = m * (1.f - u_r[j]);
                    ymu_r[j] = yo_r[j] + mg * (nsv - yo_r[j]);
                }
                hwrite4(s_yc, traj, nbase, ymu_r[0], ymu_r[1], ymu_r[2], ymu_r[3]);
            } else {
                int sb = nbase - 64;
                s4 mm = sread4(s_x[cur], traj, nbase);
                f4 u4 = *(const f4*)(s_u + traj * SYO + sb);
#pragma unroll
                for (int j = 0; j < 4; ++j) {
                    float nsv = fabsf(fn[j] + b4[j]);
                    float m = b2f((u16)mm[j]);
                    float mg = m * (1.f - u4[j]);
                    float nss = s_r[j] + mg * (nsv - s_r[j]);
                    s_r[j] = fabsf(nss);
                }
                hwrite4(s_yc, traj, nbase, s_r[0], s_r[1], s_r[2], s_r[3]);
            }
        }
        __syncthreads();
    }

    // ---- Final: z = mlp2([y|s], tz) ----
    s8 wt1[4], wt2[4];
#pragma unroll
    for (int ks = 0; ks < 4; ++ks) {
        wt1[ks] = WLOAD(OFF_TZ1, 4, w, ks);
        wt2[ks] = WLOAD(OFF_TZ2, 4, w, ks);
    }
    {
        f4 t1 = zero4;
#pragma unroll
        for (int ks = 0; ks < 4; ++ks) t1 = MFMA(wt1[ks], aread(s_yc, lane, ks), t1);
        f4 b4 = *(const f4*)(s_b + TB1 + nbase);
        hwrite4(s_hA, traj, nbase, tanh_(t1[0] + b4[0]), tanh_(t1[1] + b4[1]),
                tanh_(t1[2] + b4[2]), tanh_(t1[3] + b4[3]));
    }
    __syncthreads();
    {
        f4 t2 = zero4;
#pragma unroll
        for (int ks = 0; ks < 4; ++ks) t2 = MFMA(wt2[ks], aread(s_hA, lane, ks), t2);
        f4 b4 = *(const f4*)(s_b + TB2 + nbase);
        if (traj < MROWS) {
            int gtraj = btraj + traj;
            f4 z;
            size_t base;
            if (w < 4) {
#pragma unroll
                for (int j = 0; j < 4; ++j) z[j] = t2[j] + b4[j];
                base = (size_t)gtraj * 64 + nbase;
            } else {
#pragma unroll
                for (int j = 0; j < 4; ++j) z[j] = fabsf(t2[j] + b4[j]);
                base = (size_t)N_TRAJ * 64 + (size_t)gtraj * 64 + (nbase - 64);
            }
            if (isf32) {
                *(f4*)((float*)p.out + base) = z;
            } else {
                uint2 pv;
                pv.x = cvtpk(z[0], z[1]);
                pv.y = cvtpk(z[2], z[3]);
                *(uint2*)((u16*)p.out + base) = pv;
            }
        }
    }
}

extern "C" void kernel_launch(void* const* d_in, const int* in_sizes, int n_in,
                              void* d_out, int out_size, void* d_ws, size_t ws_size,
                              hipStream_t stream) {
    PackP pp;
    const int srcIdx[10] = {2, 6, 10, 14, 4, 8, 12, 16, 18, 20};
    const int Kr[10] = {256, 256, 256, 64, 100, 100, 100, 100, 128, 100};
    const int Nr[10] = {100, 100, 100, 100, 64, 64, 128, 64, 100, 128};
    const int KS[10] = {8, 8, 8, 2, 4, 4, 4, 4, 4, 4};
    const int NT[10] = {8, 8, 8, 8, 4, 4, 8, 4, 8, 8};
    for (int i = 0; i < 10; ++i) {
        pp.src[i] = d_in[srcIdx[i]];
        pp.Kr[i] = Kr[i];
        pp.Nr[i] = Nr[i];
        pp.KS[i] = KS[i];
        pp.sz[i] = KS[i] * NT[i] * 512;
    }
    pp.tps = d_in[1];
    repack_kernel<<<(PACK_ELEMS + 255) / 256, 256, 0, stream>>>(pp);

    PrepP bp;
    bp.tps = d_in[1];
    bp.ob1 = d_in[15]; bp.ob2 = d_in[17];
    bp.ub1 = d_in[3];  bp.ub2 = d_in[5];
    bp.rb1 = d_in[7];  bp.rb2 = d_in[9];
    bp.nb1 = d_in[11]; bp.nb2 = d_in[13];
    bp.tb1 = d_in[19]; bp.tb2 = d_in[21];
    prep_bias<<<1, 256, 0, stream>>>(bp);

    MainP mp;
    mp.data = d_in[0];
    mp.tps = d_in[1];
    mp.out = d_out;
    enc_main<<<N_TRAJ / MROWS, 512, 0, stream>>>(mp);
}

// Round 12
// 358.208 us; speedup vs baseline: 2.2439x; 2.2439x over previous
//
#include <hip/hip_runtime.h>

typedef unsigned short u16;
typedef __attribute__((ext_vector_type(8))) short s8;
typedef __attribute__((ext_vector_type(4))) short s4;
typedef __attribute__((ext_vector_type(4))) float f4;

#define N_TRAJ 4096
#define TSTEPS 128
#define LATD   64
#define INPD   128

// bias offsets (floats)
#define OB1 0
#define OB2 128
#define UB1 192
#define UB2 320
#define RB1 384
#define RB2 512
#define NB1 576
#define NB2 704
#define TB1 832
#define TB2 960
#define DTS 1088
#define NBIAS 1216

// packed weight offsets (elements)
#define OFF_UG1 0
#define OFF_RG1 32768
#define OFF_NS1 65536
#define OFF_OD1 98304
#define OFF_UG2 106496
#define OFF_RG2 114688
#define OFF_NS2 122880
#define OFF_OD2 139264
#define OFF_TZ1 147456
#define OFF_TZ2 163840
#define PACK_ELEMS 180224

#define SYO 68   // f32 state stride

__device__ u16 g_pack[PACK_ELEMS];
__device__ float g_bias[NBIAS];

__device__ __forceinline__ float b2f(u16 u) {
    union { unsigned int i; float f; } v; v.i = ((unsigned int)u) << 16; return v.f;
}
__device__ __forceinline__ u16 f2b(float f) {
    unsigned int x = __float_as_uint(f);
    unsigned int r = (x + 0x7FFFu + ((x >> 16) & 1u)) >> 16;
    return (u16)r;
}
__device__ __forceinline__ unsigned int cvtpk(float lo, float hi) {
    unsigned int r;
    asm("v_cvt_pk_bf16_f32 %0, %1, %2" : "=v"(r) : "v"(lo), "v"(hi));
    return r;
}
__device__ __forceinline__ int is_f32(const void* tps) {
    return (*(const unsigned int*)tps) == 0u;
}
__device__ __forceinline__ float rdany(const void* a, int i, int isf32) {
    return isf32 ? ((const float*)a)[i] : b2f(((const u16*)a)[i]);
}
__device__ __forceinline__ float sigm(float x) {
    x = fminf(fmaxf(x, -30.f), 30.f);
    float e = __expf(-x);
    return __builtin_amdgcn_rcpf(1.f + e);
}
__device__ __forceinline__ float tanh_(float x) {
    x = fminf(fmaxf(x, -15.f), 15.f);
    float e = __expf(-2.f * x);
    return (1.f - e) * __builtin_amdgcn_rcpf(1.f + e);
}

// activation fragment read (MFMA B operand): lane l -> traj = l&15, k = ks*32 + (l>>4)*8 + i
__device__ __forceinline__ s8 aread(const u16* buf, int lane, int ks) {
    int row = lane & 15;
    int b = (ks << 6) + ((lane >> 4) << 4);
    int off = (row << 8) + (b ^ ((row & 7) << 4));
    return *(const s8*)((const char*)buf + off);
}
__device__ __forceinline__ void hwrite4(u16* buf, int traj, int ncol0, float a, float b, float c, float d) {
    int off = (traj << 8) + ((ncol0 << 1) ^ ((traj & 7) << 4));
    uint2 v;
    v.x = cvtpk(a, b);
    v.y = cvtpk(c, d);
    *(uint2*)((char*)buf + off) = v;
}
__device__ __forceinline__ s4 sread4(const u16* buf, int traj, int col0) {
    int off = (traj << 8) + ((col0 << 1) ^ ((traj & 7) << 4));
    return *(const s4*)((const char*)buf + off);
}
__device__ __forceinline__ s4 load_x4(const void* data, size_t elemIdx, int isf32) {
    s4 r;
    if (isf32) {
        f4 v = *(const f4*)((const float*)data + elemIdx);
#pragma unroll
        for (int j = 0; j < 4; ++j) r[j] = (short)f2b(v[j]);
    } else {
        r = *(const s4*)((const u16*)data + elemIdx);
    }
    return r;
}

struct PackP {
    const void* src[10];
    const void* tps;
    int Kr[10], Nr[10], KS[10], sz[10];
};

__global__ __launch_bounds__(256) void repack_kernel(PackP p) {
    int gid = blockIdx.x * 256 + threadIdx.x;
    if (gid >= PACK_ELEMS) return;
    int isf32 = is_f32(p.tps);
    int idx = gid, m = 0, base = 0;
    while (m < 10 && idx >= p.sz[m]) { idx -= p.sz[m]; base += p.sz[m]; ++m; }
    if (m >= 10) return;
    int i = idx & 7;
    int l = (idx >> 3) & 63;
    int rest = idx >> 9;
    int ks = rest % p.KS[m];
    int nt = rest / p.KS[m];
    int k = ks * 32 + ((l >> 4) << 3) + i;
    int n = nt * 16 + (l & 15);
    u16 v = 0;
    if (k < p.Kr[m] && n < p.Nr[m]) v = f2b(rdany(p.src[m], k * p.Nr[m] + n, isf32));
    g_pack[base + idx] = v;
}

struct PrepP {
    const void *tps, *ob1, *ob2, *ub1, *ub2, *rb1, *rb2, *nb1, *nb2, *tb1, *tb2;
};

__global__ __launch_bounds__(256) void prep_bias(PrepP p) {
    int isf32 = is_f32(p.tps);
    int tid = threadIdx.x;
    for (int i = tid; i < 128; i += 256) {
        g_bias[OB1 + i] = (i < 100) ? rdany(p.ob1, i, isf32) : 0.f;
        g_bias[UB1 + i] = (i < 100) ? rdany(p.ub1, i, isf32) : 0.f;
        g_bias[RB1 + i] = (i < 100) ? rdany(p.rb1, i, isf32) : 0.f;
        g_bias[NB1 + i] = (i < 100) ? rdany(p.nb1, i, isf32) : 0.f;
        g_bias[TB1 + i] = (i < 100) ? rdany(p.tb1, i, isf32) : 0.f;
        g_bias[NB2 + i] = rdany(p.nb2, i, isf32);
        g_bias[TB2 + i] = rdany(p.tb2, i, isf32);
        g_bias[DTS + i] = (i == 0) ? -0.01f
                                   : (rdany(p.tps, 127 - i, isf32) - rdany(p.tps, 128 - i, isf32));
    }
    for (int i = tid; i < 64; i += 256) {
        g_bias[OB2 + i] = rdany(p.ob2, i, isf32);
        g_bias[UB2 + i] = rdany(p.ub2, i, isf32);
        g_bias[RB2 + i] = rdany(p.rb2, i, isf32);
    }
}

struct MainP {
    const void *data, *tps;
    void* out;
};

#define WLOAD(off, KSn, nt, ks) (*(const s8*)(pk + (off) + (((((nt) * (KSn)) + (ks)) << 6) + lane) * 8))
// TRANSPOSED: A = weight fragment, B = activation fragment -> C[ncol][traj]
#define MFMA(wf, af, c) __builtin_amdgcn_mfma_f32_16x16x32_bf16((wf), (af), (c), 0, 0, 0)

__global__ __launch_bounds__(512, 2) void enc_main(MainP p) {
    __shared__ u16 s_x[2][2048];   // [16][128] bf16 swizzled, double buffered
    __shared__ u16 s_yc[2048];     // [y | s]
    __shared__ u16 s_yc2[2048];    // [y_ode*r | s*r]
    __shared__ u16 s_hA[2048];     // h buffer (hode/hu/hns)
    __shared__ u16 s_hB[2048];     // hr
    __shared__ float s_yo[16 * SYO];
    __shared__ float s_u[16 * SYO];
    __shared__ float s_b[NBIAS];

    int tid = threadIdx.x, lane = tid & 63, w = tid >> 6;   // w = 0..7
    int btraj = blockIdx.x << 4;
    const u16* pk = g_pack;
    int isf32 = is_f32(p.tps);

    for (int i = tid; i < NBIAS; i += 512) s_b[i] = g_bias[i];
    for (int i = tid; i < 2048; i += 512) s_yc[i] = 0;

    // persistent per-wave weight fragments (nt = w), ALL layers in registers
    s8 wl1u[8], wl1r[8], wl1n[8];
    s8 wod1[2];
    s8 wod2[4], w2x[4], wn2[4];
#pragma unroll
    for (int ks = 0; ks < 8; ++ks) {
        wl1u[ks] = WLOAD(OFF_UG1, 8, w, ks);
        wl1r[ks] = WLOAD(OFF_RG1, 8, w, ks);
        wl1n[ks] = WLOAD(OFF_NS1, 8, w, ks);
    }
    wod1[0] = WLOAD(OFF_OD1, 2, w, 0);
    wod1[1] = WLOAD(OFF_OD1, 2, w, 1);
#pragma unroll
    for (int ks = 0; ks < 4; ++ks) {
        wod2[ks] = WLOAD(OFF_OD2, 4, (w & 3), ks);
        wn2[ks] = WLOAD(OFF_NS2, 4, w, ks);
    }
    if (w < 4) {
#pragma unroll
        for (int ks = 0; ks < 4; ++ks) w2x[ks] = WLOAD(OFF_UG2, 4, w, ks);
    } else {
#pragma unroll
        for (int ks = 0; ks < 4; ++ks) w2x[ks] = WLOAD(OFF_RG2, 4, w - 4, ks);
    }

    f4 ymu_r = {0.f, 0.f, 0.f, 0.f};
    f4 s_r = {0.f, 0.f, 0.f, 0.f};
    f4 yo_r = {0.f, 0.f, 0.f, 0.f};
    f4 u_r = {0.f, 0.f, 0.f, 0.f};

    // x prefetch
    int xrow = tid >> 5, xk = tid & 31;
    int xoff = (xrow << 8) + ((xk << 3) ^ ((xrow & 7) << 4));
    {
        s4 xr = load_x4(p.data, ((size_t)(btraj + xrow) * TSTEPS + 127) * INPD + (xk << 2), isf32);
        *(s4*)((char*)s_x[0] + xoff) = xr;
    }
    __syncthreads();

    const f4 zero4 = {0.f, 0.f, 0.f, 0.f};
    int traj = lane & 15;
    int nbase = (w << 4) + ((lane >> 4) << 2);   // first of 4 owned output cols (0..127)

    for (int it = 0; it < TSTEPS; ++it) {
        int cur = it & 1;
        float dt = s_b[DTS + it];

        s4 xnext;
        if (it < 127) {
            xnext = load_x4(p.data, ((size_t)(btraj + xrow) * TSTEPS + (126 - it)) * INPD + (xk << 2), isf32);
        }

        // split accumulators (chains halved; summed at use site)
        f4 au0 = zero4, au1 = zero4, ar0 = zero4, ar1 = zero4;
        f4 an0 = zero4, an1 = zero4;
        s8 ax0, ax1, ax2, ax3;

        // ---- Phase A: ode1 + u1/r1 partials over s (ks2,3) and x (ks4-7) ----
        {
            ax0 = aread(s_x[cur], lane, 0);
            ax1 = aread(s_x[cur], lane, 1);
            ax2 = aread(s_x[cur], lane, 2);
            ax3 = aread(s_x[cur], lane, 3);
            s8 ay0 = aread(s_yc, lane, 0);
            s8 ay1 = aread(s_yc, lane, 1);
            s8 ay2 = aread(s_yc, lane, 2);
            s8 ay3 = aread(s_yc, lane, 3);
            f4 ao = zero4;
            ao = MFMA(wod1[0], ay0, ao);
            ao = MFMA(wod1[1], ay1, ao);
            au0 = MFMA(wl1u[2], ay2, au0);
            ar0 = MFMA(wl1r[2], ay2, ar0);
            au0 = MFMA(wl1u[3], ay3, au0);
            ar0 = MFMA(wl1r[3], ay3, ar0);
            au0 = MFMA(wl1u[4], ax0, au0);
            ar0 = MFMA(wl1r[4], ax0, ar0);
            au0 = MFMA(wl1u[5], ax1, au0);
            ar0 = MFMA(wl1r[5], ax1, ar0);
            au1 = MFMA(wl1u[6], ax2, au1);
            ar1 = MFMA(wl1r[6], ax2, ar1);
            au1 = MFMA(wl1u[7], ax3, au1);
            ar1 = MFMA(wl1r[7], ax3, ar1);
            f4 b4 = *(const f4*)(s_b + OB1 + nbase);
            hwrite4(s_hA, traj, nbase, tanh_(ao[0] + b4[0]), tanh_(ao[1] + b4[1]),
                    tanh_(ao[2] + b4[2]), tanh_(ao[3] + b4[3]));
        }
        __syncthreads();

        // ---- Phase B: ode2 (waves 0-3) / ns1 x-part (waves 4-7) ----
        if (w < 4) {
            f4 ac0 = zero4, ac1 = zero4;
            ac0 = MFMA(wod2[0], aread(s_hA, lane, 0), ac0);
            ac1 = MFMA(wod2[2], aread(s_hA, lane, 2), ac1);
            ac0 = MFMA(wod2[1], aread(s_hA, lane, 1), ac0);
            ac1 = MFMA(wod2[3], aread(s_hA, lane, 3), ac1);
            f4 b4 = *(const f4*)(s_b + OB2 + nbase);
#pragma unroll
            for (int j = 0; j < 4; ++j) yo_r[j] = ymu_r[j] + (ac0[j] + ac1[j] + b4[j]) * dt;
            *(f4*)(s_yo + traj * SYO + nbase) = yo_r;
            hwrite4(s_yc, traj, nbase, yo_r[0], yo_r[1], yo_r[2], yo_r[3]);
        } else {
            an0 = MFMA(wl1n[4], ax0, an0);
            an1 = MFMA(wl1n[6], ax2, an1);
            an0 = MFMA(wl1n[5], ax1, an0);
            an1 = MFMA(wl1n[7], ax3, an1);
        }
        __syncthreads();

        // ---- Phase C: u1/r1 finish with y_ode part (ks0,1) ----
        {
            s8 a0 = aread(s_yc, lane, 0);
            s8 a1 = aread(s_yc, lane, 1);
            au1 = MFMA(wl1u[0], a0, au1);
            ar1 = MFMA(wl1r[0], a0, ar1);
            au1 = MFMA(wl1u[1], a1, au1);
            ar1 = MFMA(wl1r[1], a1, ar1);
            f4 bu4 = *(const f4*)(s_b + UB1 + nbase);
            f4 br4 = *(const f4*)(s_b + RB1 + nbase);
            hwrite4(s_hA, traj, nbase,
                    tanh_(au0[0] + au1[0] + bu4[0]), tanh_(au0[1] + au1[1] + bu4[1]),
                    tanh_(au0[2] + au1[2] + bu4[2]), tanh_(au0[3] + au1[3] + bu4[3]));
            hwrite4(s_hB, traj, nbase,
                    tanh_(ar0[0] + ar1[0] + br4[0]), tanh_(ar0[1] + ar1[1] + br4[1]),
                    tanh_(ar0[2] + ar1[2] + br4[2]), tanh_(ar0[3] + ar1[3] + br4[3]));
        }
        __syncthreads();

        // ---- Phase D: ns1 x-part+u2 (waves 0-3) / r2 + build yc2 (waves 4-7) ----
        if (w < 4) {
            an0 = MFMA(wl1n[4], ax0, an0);
            an1 = MFMA(wl1n[6], ax2, an1);
            an0 = MFMA(wl1n[5], ax1, an0);
            an1 = MFMA(wl1n[7], ax3, an1);
            f4 uac0 = zero4, uac1 = zero4;
            uac0 = MFMA(w2x[0], aread(s_hA, lane, 0), uac0);
            uac1 = MFMA(w2x[2], aread(s_hA, lane, 2), uac1);
            uac0 = MFMA(w2x[1], aread(s_hA, lane, 1), uac0);
            uac1 = MFMA(w2x[3], aread(s_hA, lane, 3), uac1);
            f4 b4 = *(const f4*)(s_b + UB2 + nbase);
#pragma unroll
            for (int j = 0; j < 4; ++j) u_r[j] = sigm(uac0[j] + uac1[j] + b4[j]);
            *(f4*)(s_u + traj * SYO + nbase) = u_r;
        } else {
            f4 rac0 = zero4, rac1 = zero4;
            rac0 = MFMA(w2x[0], aread(s_hB, lane, 0), rac0);
            rac1 = MFMA(w2x[2], aread(s_hB, lane, 2), rac1);
            rac0 = MFMA(w2x[1], aread(s_hB, lane, 1), rac0);
            rac1 = MFMA(w2x[3], aread(s_hB, lane, 3), rac1);
            int sb = nbase - 64;
            f4 b4 = *(const f4*)(s_b + RB2 + sb);
            f4 yo4 = *(const f4*)(s_yo + traj * SYO + sb);
            f4 rv;
#pragma unroll
            for (int j = 0; j < 4; ++j) rv[j] = sigm(rac0[j] + rac1[j] + b4[j]);
            hwrite4(s_yc2, traj, sb, yo4[0] * rv[0], yo4[1] * rv[1], yo4[2] * rv[2], yo4[3] * rv[3]);
            hwrite4(s_yc2, traj, nbase, s_r[0] * rv[0], s_r[1] * rv[1], s_r[2] * rv[2], s_r[3] * rv[3]);
        }
        __syncthreads();

        // ---- Phase E: ns1 finish (yc2 part), all waves ----
        {
            an0 = MFMA(wl1n[0], aread(s_yc2, lane, 0), an0);
            an1 = MFMA(wl1n[2], aread(s_yc2, lane, 2), an1);
            an0 = MFMA(wl1n[1], aread(s_yc2, lane, 1), an0);
            an1 = MFMA(wl1n[3], aread(s_yc2, lane, 3), an1);
            f4 b4 = *(const f4*)(s_b + NB1 + nbase);
            hwrite4(s_hA, traj, nbase,
                    tanh_(an0[0] + an1[0] + b4[0]), tanh_(an0[1] + an1[1] + b4[1]),
                    tanh_(an0[2] + an1[2] + b4[2]), tanh_(an0[3] + an1[3] + b4[3]));
        }
        __syncthreads();

        // ---- Phase F: ns2 + state update, all waves ----
        {
            f4 fn0 = zero4, fn1 = zero4;
            fn0 = MFMA(wn2[0], aread(s_hA, lane, 0), fn0);
            fn1 = MFMA(wn2[2], aread(s_hA, lane, 2), fn1);
            fn0 = MFMA(wn2[1], aread(s_hA, lane, 1), fn0);
            fn1 = MFMA(wn2[3], aread(s_hA, lane, 3), fn1);
            if (it < 127) *(s4*)((char*)s_x[cur ^ 1] + xoff) = xnext;

            f4 b4 = *(const f4*)(s_b + NB2 + nbase);
            if (w < 4) {
                s4 mm = sread4(s_x[cur], traj, 64 + nbase);
#pragma unroll
                for (int j = 0; j < 4; ++j) {
                    float nsv = fn0[j] + fn1[j] + b4[j];
                    float m = b2f((u16)mm[j]);
                    float mg = m * (1.f - u_r[j]);
                    ymu_r[j] = yo_r[j] + mg * (nsv - yo_r[j]);
                }
                hwrite4(s_yc, traj, nbase, ymu_r[0], ymu_r[1], ymu_r[2], ymu_r[3]);
            } else {
                int sb = nbase - 64;
                s4 mm = sread4(s_x[cur], traj, nbase);
                f4 u4 = *(const f4*)(s_u + traj * SYO + sb);
#pragma unroll
                for (int j = 0; j < 4; ++j) {
                    float nsv = fabsf(fn0[j] + fn1[j] + b4[j]);
                    float m = b2f((u16)mm[j]);
                    float mg = m * (1.f - u4[j]);
                    float nss = s_r[j] + mg * (nsv - s_r[j]);
                    s_r[j] = fabsf(nss);
                }
                hwrite4(s_yc, traj, nbase, s_r[0], s_r[1], s_r[2], s_r[3]);
            }
        }
        __syncthreads();
    }

    // ---- Final: z = mlp2([y|s], tz) ----
    s8 wt1[4], wt2[4];
#pragma unroll
    for (int ks = 0; ks < 4; ++ks) {
        wt1[ks] = WLOAD(OFF_TZ1, 4, w, ks);
        wt2[ks] = WLOAD(OFF_TZ2, 4, w, ks);
    }
    {
        f4 t1 = zero4;
#pragma unroll
        for (int ks = 0; ks < 4; ++ks) t1 = MFMA(wt1[ks], aread(s_yc, lane, ks), t1);
        f4 b4 = *(const f4*)(s_b + TB1 + nbase);
        hwrite4(s_hA, traj, nbase, tanh_(t1[0] + b4[0]), tanh_(t1[1] + b4[1]),
                tanh_(t1[2] + b4[2]), tanh_(t1[3] + b4[3]));
    }
    __syncthreads();
    {
        f4 t2 = zero4;
#pragma unroll
        for (int ks = 0; ks < 4; ++ks) t2 = MFMA(wt2[ks], aread(s_hA, lane, ks), t2);
        f4 b4 = *(const f4*)(s_b + TB2 + nbase);
        int gtraj = btraj + traj;
        f4 z;
        size_t base;
        if (w < 4) {
#pragma unroll
            for (int j = 0; j < 4; ++j) z[j] = t2[j] + b4[j];
            base = (size_t)gtraj * 64 + nbase;
        } else {
#pragma unroll
            for (int j = 0; j < 4; ++j) z[j] = fabsf(t2[j] + b4[j]);
            base = (size_t)N_TRAJ * 64 + (size_t)gtraj * 64 + (nbase - 64);
        }
        if (isf32) {
            *(f4*)((float*)p.out + base) = z;
        } else {
            uint2 pv;
            pv.x = cvtpk(z[0], z[1]);
            pv.y = cvtpk(z[2], z[3]);
            *(uint2*)((u16*)p.out + base) = pv;
        }
    }
}

extern "C" void kernel_launch(void* const* d_in, const int* in_sizes, int n_in,
                              void* d_out, int out_size, void* d_ws, size_t ws_size,
                              hipStream_t stream) {
    PackP pp;
    const int srcIdx[10] = {2, 6, 10, 14, 4, 8, 12, 16, 18, 20};
    const int Kr[10] = {256, 256, 256, 64, 100, 100, 100, 100, 128, 100};
    const int Nr[10] = {100, 100, 100, 100, 64, 64, 128, 64, 100, 128};
    const int KS[10] = {8, 8, 8, 2, 4, 4, 4, 4, 4, 4};
    const int NT[10] = {8, 8, 8, 8, 4, 4, 8, 4, 8, 8};
    for (int i = 0; i < 10; ++i) {
        pp.src[i] = d_in[srcIdx[i]];
        pp.Kr[i] = Kr[i];
        pp.Nr[i] = Nr[i];
        pp.KS[i] = KS[i];
        pp.sz[i] = KS[i] * NT[i] * 512;
    }
    pp.tps = d_in[1];
    repack_kernel<<<(PACK_ELEMS + 255) / 256, 256, 0, stream>>>(pp);

    PrepP bp;
    bp.tps = d_in[1];
    bp.ob1 = d_in[15]; bp.ob2 = d_in[17];
    bp.ub1 = d_in[3];  bp.ub2 = d_in[5];
    bp.rb1 = d_in[7];  bp.rb2 = d_in[9];
    bp.nb1 = d_in[11]; bp.nb2 = d_in[13];
    bp.tb1 = d_in[19]; bp.tb2 = d_in[21];
    prep_bias<<<1, 256, 0, stream>>>(bp);

    MainP mp;
    mp.data = d_in[0];
    mp.tps = d_in[1];
    mp.out = d_out;
    enc_main<<<N_TRAJ / 16, 512, 0, stream>>>(mp);
}

// Round 13
// 342.400 us; speedup vs baseline: 2.3475x; 1.0462x over previous
//
#include <hip/hip_runtime.h>

typedef unsigned short u16;
typedef __attribute__((ext_vector_type(8))) short s8;
typedef __attribute__((ext_vector_type(4))) short s4;
typedef __attribute__((ext_vector_type(4))) float f4;

#define N_TRAJ 4096
#define TSTEPS 128
#define LATD   64
#define INPD   128

// bias offsets (floats)
#define OB1 0
#define OB2 128
#define UB1 192
#define UB2 320
#define RB1 384
#define RB2 512
#define NB1 576
#define NB2 704
#define TB1 832
#define TB2 960
#define DTS 1088
#define NBIAS 1216

// packed weight offsets (elements)
#define OFF_UG1 0
#define OFF_RG1 32768
#define OFF_NS1 65536
#define OFF_OD1 98304
#define OFF_UG2 106496
#define OFF_RG2 114688
#define OFF_NS2 122880
#define OFF_OD2 139264
#define OFF_TZ1 147456
#define OFF_TZ2 163840
#define PACK_ELEMS 180224

#define SYO 68   // f32 state stride

__device__ u16 g_pack[PACK_ELEMS];
__device__ float g_bias[NBIAS];

__device__ __forceinline__ float b2f(u16 u) {
    union { unsigned int i; float f; } v; v.i = ((unsigned int)u) << 16; return v.f;
}
__device__ __forceinline__ u16 f2b(float f) {
    unsigned int x = __float_as_uint(f);
    unsigned int r = (x + 0x7FFFu + ((x >> 16) & 1u)) >> 16;
    return (u16)r;
}
__device__ __forceinline__ unsigned int cvtpk(float lo, float hi) {
    unsigned int r;
    asm("v_cvt_pk_bf16_f32 %0, %1, %2" : "=v"(r) : "v"(lo), "v"(hi));
    return r;
}
__device__ __forceinline__ int is_f32(const void* tps) {
    return (*(const unsigned int*)tps) == 0u;
}
__device__ __forceinline__ float rdany(const void* a, int i, int isf32) {
    return isf32 ? ((const float*)a)[i] : b2f(((const u16*)a)[i]);
}
__device__ __forceinline__ float sigm(float x) {
    x = fminf(fmaxf(x, -30.f), 30.f);
    float e = __expf(-x);
    return __builtin_amdgcn_rcpf(1.f + e);
}
__device__ __forceinline__ float tanh_(float x) {
    x = fminf(fmaxf(x, -15.f), 15.f);
    float e = __expf(-2.f * x);
    return __builtin_fmaf(2.f, __builtin_amdgcn_rcpf(1.f + e), -1.f);
}

// activation fragment read (MFMA B operand): lane l -> traj = l&15, k = ks*32 + (l>>4)*8 + i
__device__ __forceinline__ s8 aread(const u16* buf, int lane, int ks) {
    int row = lane & 15;
    int b = (ks << 6) + ((lane >> 4) << 4);
    int off = (row << 8) + (b ^ ((row & 7) << 4));
    return *(const s8*)((const char*)buf + off);
}
__device__ __forceinline__ void hwrite4(u16* buf, int traj, int ncol0, float a, float b, float c, float d) {
    int off = (traj << 8) + ((ncol0 << 1) ^ ((traj & 7) << 4));
    uint2 v;
    v.x = cvtpk(a, b);
    v.y = cvtpk(c, d);
    *(uint2*)((char*)buf + off) = v;
}
__device__ __forceinline__ s4 sread4(const u16* buf, int traj, int col0) {
    int off = (traj << 8) + ((col0 << 1) ^ ((traj & 7) << 4));
    return *(const s4*)((const char*)buf + off);
}
__device__ __forceinline__ s4 load_x4(const void* data, size_t elemIdx, int isf32) {
    s4 r;
    if (isf32) {
        f4 v = *(const f4*)((const float*)data + elemIdx);
#pragma unroll
        for (int j = 0; j < 4; ++j) r[j] = (short)f2b(v[j]);
    } else {
        r = *(const s4*)((const u16*)data + elemIdx);
    }
    return r;
}

struct PackP {
    const void* src[10];
    const void* tps;
    int Kr[10], Nr[10], KS[10], sz[10];
};

__global__ __launch_bounds__(256) void repack_kernel(PackP p) {
    int gid = blockIdx.x * 256 + threadIdx.x;
    if (gid >= PACK_ELEMS) return;
    int isf32 = is_f32(p.tps);
    int idx = gid, m = 0, base = 0;
    while (m < 10 && idx >= p.sz[m]) { idx -= p.sz[m]; base += p.sz[m]; ++m; }
    if (m >= 10) return;
    int i = idx & 7;
    int l = (idx >> 3) & 63;
    int rest = idx >> 9;
    int ks = rest % p.KS[m];
    int nt = rest / p.KS[m];
    int k = ks * 32 + ((l >> 4) << 3) + i;
    int n = nt * 16 + (l & 15);
    u16 v = 0;
    if (k < p.Kr[m] && n < p.Nr[m]) v = f2b(rdany(p.src[m], k * p.Nr[m] + n, isf32));
    g_pack[base + idx] = v;
}

struct PrepP {
    const void *tps, *ob1, *ob2, *ub1, *ub2, *rb1, *rb2, *nb1, *nb2, *tb1, *tb2;
};

__global__ __launch_bounds__(256) void prep_bias(PrepP p) {
    int isf32 = is_f32(p.tps);
    int tid = threadIdx.x;
    for (int i = tid; i < 128; i += 256) {
        g_bias[OB1 + i] = (i < 100) ? rdany(p.ob1, i, isf32) : 0.f;
        g_bias[UB1 + i] = (i < 100) ? rdany(p.ub1, i, isf32) : 0.f;
        g_bias[RB1 + i] = (i < 100) ? rdany(p.rb1, i, isf32) : 0.f;
        g_bias[NB1 + i] = (i < 100) ? rdany(p.nb1, i, isf32) : 0.f;
        g_bias[TB1 + i] = (i < 100) ? rdany(p.tb1, i, isf32) : 0.f;
        g_bias[NB2 + i] = rdany(p.nb2, i, isf32);
        g_bias[TB2 + i] = rdany(p.tb2, i, isf32);
        g_bias[DTS + i] = (i == 0) ? -0.01f
                                   : (rdany(p.tps, 127 - i, isf32) - rdany(p.tps, 128 - i, isf32));
    }
    for (int i = tid; i < 64; i += 256) {
        g_bias[OB2 + i] = rdany(p.ob2, i, isf32);
        g_bias[UB2 + i] = rdany(p.ub2, i, isf32);
        g_bias[RB2 + i] = rdany(p.rb2, i, isf32);
    }
}

struct MainP {
    const void *data, *tps;
    void* out;
};

#define WLOAD(off, KSn, nt, ks) (*(const s8*)(pk + (off) + (((((nt) * (KSn)) + (ks)) << 6) + lane) * 8))
// TRANSPOSED: A = weight fragment, B = activation fragment -> C[ncol][traj]
#define MFMA(wf, af, c) __builtin_amdgcn_mfma_f32_16x16x32_bf16((wf), (af), (c), 0, 0, 0)

__global__ __launch_bounds__(512, 2) void enc_main(MainP p) {
    __shared__ u16 s_x[2][2048];   // [16][128] bf16 swizzled, double buffered
    __shared__ u16 s_yc[2048];     // [y | s]
    __shared__ u16 s_yc2[2048];    // [y_ode*r | s*r]
    __shared__ u16 s_hA[2048];     // h buffer (hode/hu/hns)
    __shared__ u16 s_hB[2048];     // hr
    __shared__ float s_yo[16 * SYO];
    __shared__ float s_u[16 * SYO];
    __shared__ float s_b[NBIAS];

    int tid = threadIdx.x, lane = tid & 63, w = tid >> 6;   // w = 0..7
    int btraj = blockIdx.x << 4;
    const u16* pk = g_pack;
    int isf32 = is_f32(p.tps);

    for (int i = tid; i < NBIAS; i += 512) s_b[i] = g_bias[i];
    for (int i = tid; i < 2048; i += 512) s_yc[i] = 0;

    // persistent per-wave weight fragments (nt = w), ALL layers in registers
    s8 wl1u[8], wl1r[8], wl1n[8];
    s8 wod1[2];
    s8 wod2[4], w2x[4], wn2[4];
#pragma unroll
    for (int ks = 0; ks < 8; ++ks) {
        wl1u[ks] = WLOAD(OFF_UG1, 8, w, ks);
        wl1r[ks] = WLOAD(OFF_RG1, 8, w, ks);
        wl1n[ks] = WLOAD(OFF_NS1, 8, w, ks);
    }
    wod1[0] = WLOAD(OFF_OD1, 2, w, 0);
    wod1[1] = WLOAD(OFF_OD1, 2, w, 1);
#pragma unroll
    for (int ks = 0; ks < 4; ++ks) {
        wod2[ks] = WLOAD(OFF_OD2, 4, (w & 3), ks);
        wn2[ks] = WLOAD(OFF_NS2, 4, w, ks);
    }
    if (w < 4) {
#pragma unroll
        for (int ks = 0; ks < 4; ++ks) w2x[ks] = WLOAD(OFF_UG2, 4, w, ks);
    } else {
#pragma unroll
        for (int ks = 0; ks < 4; ++ks) w2x[ks] = WLOAD(OFF_RG2, 4, w - 4, ks);
    }

    f4 ymu_r = {0.f, 0.f, 0.f, 0.f};
    f4 s_r = {0.f, 0.f, 0.f, 0.f};
    f4 yo_r = {0.f, 0.f, 0.f, 0.f};
    f4 u_r = {0.f, 0.f, 0.f, 0.f};

    // x prefetch for step 0
    int xrow = tid >> 5, xk = tid & 31;
    int xoff = (xrow << 8) + ((xk << 3) ^ ((xrow & 7) << 4));
    {
        s4 xr = load_x4(p.data, ((size_t)(btraj + xrow) * TSTEPS + 127) * INPD + (xk << 2), isf32);
        *(s4*)((char*)s_x[0] + xoff) = xr;
    }
    __syncthreads();

    const f4 zero4 = {0.f, 0.f, 0.f, 0.f};
    int traj = lane & 15;
    int nbase = (w << 4) + ((lane >> 4) << 2);   // first of 4 owned output cols (0..127)

    // ---- prime: x fragments + u1/r1 x-partials for step 0 ----
    s8 axc0 = aread(s_x[0], lane, 0);
    s8 axc1 = aread(s_x[0], lane, 1);
    s8 axc2 = aread(s_x[0], lane, 2);
    s8 axc3 = aread(s_x[0], lane, 3);
    f4 auA = zero4, arA = zero4;    // u1/r1 partials: x (prev E/F or prime) + s (phase A)
    auA = MFMA(wl1u[4], axc0, auA);
    arA = MFMA(wl1r[4], axc0, arA);
    auA = MFMA(wl1u[5], axc1, auA);
    arA = MFMA(wl1r[5], axc1, arA);
    auA = MFMA(wl1u[6], axc2, auA);
    arA = MFMA(wl1r[6], axc2, arA);
    auA = MFMA(wl1u[7], axc3, auA);
    arA = MFMA(wl1r[7], axc3, arA);

    for (int it = 0; it < TSTEPS; ++it) {
        int cur = it & 1;
        float dt = s_b[DTS + it];

        s4 xnext;
        if (it < 127) {
            xnext = load_x4(p.data, ((size_t)(btraj + xrow) * TSTEPS + (126 - it)) * INPD + (xk << 2), isf32);
        }

        f4 an0 = zero4, an1 = zero4;

        // ---- Phase A: ode1 + u1/r1 s-partials (ks2,3) ----
        {
            s8 ay0 = aread(s_yc, lane, 0);
            s8 ay1 = aread(s_yc, lane, 1);
            s8 ay2 = aread(s_yc, lane, 2);
            s8 ay3 = aread(s_yc, lane, 3);
            f4 ao = zero4;
            ao = MFMA(wod1[0], ay0, ao);
            ao = MFMA(wod1[1], ay1, ao);
            auA = MFMA(wl1u[2], ay2, auA);
            arA = MFMA(wl1r[2], ay2, arA);
            auA = MFMA(wl1u[3], ay3, auA);
            arA = MFMA(wl1r[3], ay3, arA);
            f4 b4 = *(const f4*)(s_b + OB1 + nbase);
            hwrite4(s_hA, traj, nbase, tanh_(ao[0] + b4[0]), tanh_(ao[1] + b4[1]),
                    tanh_(ao[2] + b4[2]), tanh_(ao[3] + b4[3]));
        }
        __syncthreads();

        // ---- Phase B: ode2 (waves 0-3) / ns1 x-part (waves 4-7) ----
        if (w < 4) {
            f4 ac0 = zero4, ac1 = zero4;
            ac0 = MFMA(wod2[0], aread(s_hA, lane, 0), ac0);
            ac1 = MFMA(wod2[2], aread(s_hA, lane, 2), ac1);
            ac0 = MFMA(wod2[1], aread(s_hA, lane, 1), ac0);
            ac1 = MFMA(wod2[3], aread(s_hA, lane, 3), ac1);
            f4 b4 = *(const f4*)(s_b + OB2 + nbase);
#pragma unroll
            for (int j = 0; j < 4; ++j) yo_r[j] = ymu_r[j] + (ac0[j] + ac1[j] + b4[j]) * dt;
            *(f4*)(s_yo + traj * SYO + nbase) = yo_r;
            hwrite4(s_yc, traj, nbase, yo_r[0], yo_r[1], yo_r[2], yo_r[3]);
        } else {
            an0 = MFMA(wl1n[4], axc0, an0);
            an1 = MFMA(wl1n[6], axc2, an1);
            an0 = MFMA(wl1n[5], axc1, an0);
            an1 = MFMA(wl1n[7], axc3, an1);
        }
        __syncthreads();

        // ---- Phase C: u1/r1 finish (y_ode ks0,1); store next x tile ----
        {
            s8 a0 = aread(s_yc, lane, 0);
            s8 a1 = aread(s_yc, lane, 1);
            f4 au1 = zero4, ar1 = zero4;
            au1 = MFMA(wl1u[0], a0, au1);
            ar1 = MFMA(wl1r[0], a0, ar1);
            au1 = MFMA(wl1u[1], a1, au1);
            ar1 = MFMA(wl1r[1], a1, ar1);
            if (it < 127) *(s4*)((char*)s_x[cur ^ 1] + xoff) = xnext;
            f4 bu4 = *(const f4*)(s_b + UB1 + nbase);
            f4 br4 = *(const f4*)(s_b + RB1 + nbase);
            hwrite4(s_hA, traj, nbase,
                    tanh_(auA[0] + au1[0] + bu4[0]), tanh_(auA[1] + au1[1] + bu4[1]),
                    tanh_(auA[2] + au1[2] + bu4[2]), tanh_(auA[3] + au1[3] + bu4[3]));
            hwrite4(s_hB, traj, nbase,
                    tanh_(arA[0] + ar1[0] + br4[0]), tanh_(arA[1] + ar1[1] + br4[1]),
                    tanh_(arA[2] + ar1[2] + br4[2]), tanh_(arA[3] + ar1[3] + br4[3]));
        }
        __syncthreads();

        // ---- Phase D: ns1 x-part+u2 (waves 0-3) / r2 + build yc2 (waves 4-7) ----
        if (w < 4) {
            an0 = MFMA(wl1n[4], axc0, an0);
            an1 = MFMA(wl1n[6], axc2, an1);
            an0 = MFMA(wl1n[5], axc1, an0);
            an1 = MFMA(wl1n[7], axc3, an1);
            f4 uac0 = zero4, uac1 = zero4;
            uac0 = MFMA(w2x[0], aread(s_hA, lane, 0), uac0);
            uac1 = MFMA(w2x[2], aread(s_hA, lane, 2), uac1);
            uac0 = MFMA(w2x[1], aread(s_hA, lane, 1), uac0);
            uac1 = MFMA(w2x[3], aread(s_hA, lane, 3), uac1);
            f4 b4 = *(const f4*)(s_b + UB2 + nbase);
#pragma unroll
            for (int j = 0; j < 4; ++j) u_r[j] = sigm(uac0[j] + uac1[j] + b4[j]);
            *(f4*)(s_u + traj * SYO + nbase) = u_r;
        } else {
            f4 rac0 = zero4, rac1 = zero4;
            rac0 = MFMA(w2x[0], aread(s_hB, lane, 0), rac0);
            rac1 = MFMA(w2x[2], aread(s_hB, lane, 2), rac1);
            rac0 = MFMA(w2x[1], aread(s_hB, lane, 1), rac0);
            rac1 = MFMA(w2x[3], aread(s_hB, lane, 3), rac1);
            int sb = nbase - 64;
            f4 b4 = *(const f4*)(s_b + RB2 + sb);
            f4 yo4 = *(const f4*)(s_yo + traj * SYO + sb);
            f4 rv;
#pragma unroll
            for (int j = 0; j < 4; ++j) rv[j] = sigm(rac0[j] + rac1[j] + b4[j]);
            hwrite4(s_yc2, traj, sb, yo4[0] * rv[0], yo4[1] * rv[1], yo4[2] * rv[2], yo4[3] * rv[3]);
            hwrite4(s_yc2, traj, nbase, s_r[0] * rv[0], s_r[1] * rv[1], s_r[2] * rv[2], s_r[3] * rv[3]);
        }
        __syncthreads();

        // ---- Phase E: ns1 finish (yc2 part) + next-x u/r partials (ks4,5) ----
        s8 axn0, axn1, axn2, axn3;
        f4 auN = zero4, arN = zero4;
        {
            an0 = MFMA(wl1n[0], aread(s_yc2, lane, 0), an0);
            an1 = MFMA(wl1n[2], aread(s_yc2, lane, 2), an1);
            an0 = MFMA(wl1n[1], aread(s_yc2, lane, 1), an0);
            an1 = MFMA(wl1n[3], aread(s_yc2, lane, 3), an1);
            if (it < 127) {
                axn0 = aread(s_x[cur ^ 1], lane, 0);
                axn1 = aread(s_x[cur ^ 1], lane, 1);
                auN = MFMA(wl1u[4], axn0, auN);
                arN = MFMA(wl1r[4], axn0, arN);
                auN = MFMA(wl1u[5], axn1, auN);
                arN = MFMA(wl1r[5], axn1, arN);
            }
            f4 b4 = *(const f4*)(s_b + NB1 + nbase);
            hwrite4(s_hA, traj, nbase,
                    tanh_(an0[0] + an1[0] + b4[0]), tanh_(an0[1] + an1[1] + b4[1]),
                    tanh_(an0[2] + an1[2] + b4[2]), tanh_(an0[3] + an1[3] + b4[3]));
        }
        __syncthreads();

        // ---- Phase F: ns2 + state update + next-x u/r partials (ks6,7) ----
        {
            f4 fn0 = zero4, fn1 = zero4;
            fn0 = MFMA(wn2[0], aread(s_hA, lane, 0), fn0);
            fn1 = MFMA(wn2[2], aread(s_hA, lane, 2), fn1);
            fn0 = MFMA(wn2[1], aread(s_hA, lane, 1), fn0);
            fn1 = MFMA(wn2[3], aread(s_hA, lane, 3), fn1);
            if (it < 127) {
                axn2 = aread(s_x[cur ^ 1], lane, 2);
                axn3 = aread(s_x[cur ^ 1], lane, 3);
                auN = MFMA(wl1u[6], axn2, auN);
                arN = MFMA(wl1r[6], axn2, arN);
                auN = MFMA(wl1u[7], axn3, auN);
                arN = MFMA(wl1r[7], axn3, arN);
            }

            f4 b4 = *(const f4*)(s_b + NB2 + nbase);
            if (w < 4) {
                s4 mm = sread4(s_x[cur], traj, 64 + nbase);
#pragma unroll
                for (int j = 0; j < 4; ++j) {
                    float nsv = fn0[j] + fn1[j] + b4[j];
                    float m = b2f((u16)mm[j]);
                    float mg = m * (1.f - u_r[j]);
                    ymu_r[j] = yo_r[j] + mg * (nsv - yo_r[j]);
                }
                hwrite4(s_yc, traj, nbase, ymu_r[0], ymu_r[1], ymu_r[2], ymu_r[3]);
            } else {
                int sb = nbase - 64;
                s4 mm = sread4(s_x[cur], traj, nbase);
                f4 u4 = *(const f4*)(s_u + traj * SYO + sb);
#pragma unroll
                for (int j = 0; j < 4; ++j) {
                    float nsv = fabsf(fn0[j] + fn1[j] + b4[j]);
                    float m = b2f((u16)mm[j]);
                    float mg = m * (1.f - u4[j]);
                    float nss = s_r[j] + mg * (nsv - s_r[j]);
                    s_r[j] = fabsf(nss);
                }
                hwrite4(s_yc, traj, nbase, s_r[0], s_r[1], s_r[2], s_r[3]);
            }
        }
        __syncthreads();

        // carry next-step x fragments and partials
        if (it < 127) {
            auA = auN;
            arA = arN;
            axc0 = axn0;
            axc1 = axn1;
            axc2 = axn2;
            axc3 = axn3;
        }
    }

    // ---- Final: z = mlp2([y|s], tz) ----
    s8 wt1[4], wt2[4];
#pragma unroll
    for (int ks = 0; ks < 4; ++ks) {
        wt1[ks] = WLOAD(OFF_TZ1, 4, w, ks);
        wt2[ks] = WLOAD(OFF_TZ2, 4, w, ks);
    }
    {
        f4 t1 = zero4;
#pragma unroll
        for (int ks = 0; ks < 4; ++ks) t1 = MFMA(wt1[ks], aread(s_yc, lane, ks), t1);
        f4 b4 = *(const f4*)(s_b + TB1 + nbase);
        hwrite4(s_hA, traj, nbase, tanh_(t1[0] + b4[0]), tanh_(t1[1] + b4[1]),
                tanh_(t1[2] + b4[2]), tanh_(t1[3] + b4[3]));
    }
    __syncthreads();
    {
        f4 t2 = zero4;
#pragma unroll
        for (int ks = 0; ks < 4; ++ks) t2 = MFMA(wt2[ks], aread(s_hA, lane, ks), t2);
        f4 b4 = *(const f4*)(s_b + TB2 + nbase);
        int gtraj = btraj + traj;
        f4 z;
        size_t base;
        if (w < 4) {
#pragma unroll
            for (int j = 0; j < 4; ++j) z[j] = t2[j] + b4[j];
            base = (size_t)gtraj * 64 + nbase;
        } else {
#pragma unroll
            for (int j = 0; j < 4; ++j) z[j] = fabsf(t2[j] + b4[j]);
            base = (size_t)N_TRAJ * 64 + (size_t)gtraj * 64 + (nbase - 64);
        }
        if (isf32) {
            *(f4*)((float*)p.out + base) = z;
        } else {
            uint2 pv;
            pv.x = cvtpk(z[0], z[1]);
            pv.y = cvtpk(z[2], z[3]);
            *(uint2*)((u16*)p.out + base) = pv;
        }
    }
}

extern "C" void kernel_launch(void* const* d_in, const int* in_sizes, int n_in,
                              void* d_out, int out_size, void* d_ws, size_t ws_size,
                              hipStream_t stream) {
    PackP pp;
    const int srcIdx[10] = {2, 6, 10, 14, 4, 8, 12, 16, 18, 20};
    const int Kr[10] = {256, 256, 256, 64, 100, 100, 100, 100, 128, 100};
    const int Nr[10] = {100, 100, 100, 100, 64, 64, 128, 64, 100, 128};
    const int KS[10] = {8, 8, 8, 2, 4, 4, 4, 4, 4, 4};
    const int NT[10] = {8, 8, 8, 8, 4, 4, 8, 4, 8, 8};
    for (int i = 0; i < 10; ++i) {
        pp.src[i] = d_in[srcIdx[i]];
        pp.Kr[i] = Kr[i];
        pp.Nr[i] = Nr[i];
        pp.KS[i] = KS[i];
        pp.sz[i] = KS[i] * NT[i] * 512;
    }
    pp.tps = d_in[1];
    repack_kernel<<<(PACK_ELEMS + 255) / 256, 256, 0, stream>>>(pp);

    PrepP bp;
    bp.tps = d_in[1];
    bp.ob1 = d_in[15]; bp.ob2 = d_in[17];
    bp.ub1 = d_in[3];  bp.ub2 = d_in[5];
    bp.rb1 = d_in[7];  bp.rb2 = d_in[9];
    bp.nb1 = d_in[11]; bp.nb2 = d_in[13];
    bp.tb1 = d_in[19]; bp.tb2 = d_in[21];
    prep_bias<<<1, 256, 0, stream>>>(bp);

    MainP mp;
    mp.data = d_in[0];
    mp.tps = d_in[1];
    mp.out = d_out;
    enc_main<<<N_TRAJ / 16, 512, 0, stream>>>(mp);
}

// Round 14
// 331.924 us; speedup vs baseline: 2.4216x; 1.0316x over previous
//
#include <hip/hip_runtime.h>

typedef unsigned short u16;
typedef __attribute__((ext_vector_type(8))) short s8;
typedef __attribute__((ext_vector_type(4))) short s4;
typedef __attribute__((ext_vector_type(4))) float f4;

#define N_TRAJ 4096
#define TSTEPS 128
#define LATD   64
#define INPD   128

// bias offsets (floats)
#define OB1 0
#define OB2 128
#define UB1 192
#define UB2 320
#define RB1 384
#define RB2 512
#define NB1 576
#define NB2 704
#define TB1 832
#define TB2 960
#define DTS 1088
#define NBIAS 1216

// packed weight offsets (elements)
#define OFF_UG1 0
#define OFF_RG1 32768
#define OFF_NS1 65536
#define OFF_OD1 98304
#define OFF_UG2 106496
#define OFF_RG2 114688
#define OFF_NS2 122880
#define OFF_OD2 139264
#define OFF_TZ1 147456
#define OFF_TZ2 163840
#define PACK_ELEMS 180224

__device__ u16 g_pack[PACK_ELEMS];
__device__ float g_bias[NBIAS];

__device__ __forceinline__ float b2f(u16 u) {
    union { unsigned int i; float f; } v; v.i = ((unsigned int)u) << 16; return v.f;
}
__device__ __forceinline__ u16 f2b(float f) {
    unsigned int x = __float_as_uint(f);
    unsigned int r = (x + 0x7FFFu + ((x >> 16) & 1u)) >> 16;
    return (u16)r;
}
__device__ __forceinline__ unsigned int cvtpk(float lo, float hi) {
    unsigned int r;
    asm("v_cvt_pk_bf16_f32 %0, %1, %2" : "=v"(r) : "v"(lo), "v"(hi));
    return r;
}
__device__ __forceinline__ int is_f32(const void* tps) {
    return (*(const unsigned int*)tps) == 0u;
}
__device__ __forceinline__ float rdany(const void* a, int i, int isf32) {
    return isf32 ? ((const float*)a)[i] : b2f(((const u16*)a)[i]);
}
// clamp-free: rcp degrades gracefully through e=inf (-> 0) and e=0 (-> 1)
__device__ __forceinline__ float sigm(float x) {
    float e = __builtin_amdgcn_exp2f(-1.4426950408889634f * x);
    return __builtin_amdgcn_rcpf(1.f + e);
}
__device__ __forceinline__ float tanh_(float x) {
    float e = __builtin_amdgcn_exp2f(-2.8853900817779268f * x);
    return __builtin_fmaf(2.f, __builtin_amdgcn_rcpf(1.f + e), -1.f);
}

// activation fragment read (MFMA B operand): lane l -> traj = l&15, k = ks*32 + (l>>4)*8 + i
__device__ __forceinline__ s8 aread(const u16* buf, int lane, int ks) {
    int row = lane & 15;
    int b = (ks << 6) + ((lane >> 4) << 4);
    int off = (row << 8) + (b ^ ((row & 7) << 4));
    return *(const s8*)((const char*)buf + off);
}
__device__ __forceinline__ void hwrite4(u16* buf, int traj, int ncol0, float a, float b, float c, float d) {
    int off = (traj << 8) + ((ncol0 << 1) ^ ((traj & 7) << 4));
    uint2 v;
    v.x = cvtpk(a, b);
    v.y = cvtpk(c, d);
    *(uint2*)((char*)buf + off) = v;
}
__device__ __forceinline__ s4 sread4(const u16* buf, int traj, int col0) {
    int off = (traj << 8) + ((col0 << 1) ^ ((traj & 7) << 4));
    return *(const s4*)((const char*)buf + off);
}
// u-tile [16][64] bf16 swizzled (row stride 128B)
__device__ __forceinline__ void uwrite4(u16* buf, int traj, int c0, float a, float b, float c, float d) {
    int off = (traj << 7) + ((c0 << 1) ^ ((traj & 7) << 4));
    uint2 v;
    v.x = cvtpk(a, b);
    v.y = cvtpk(c, d);
    *(uint2*)((char*)buf + off) = v;
}
__device__ __forceinline__ s4 uread4(const u16* buf, int traj, int c0) {
    int off = (traj << 7) + ((c0 << 1) ^ ((traj & 7) << 4));
    return *(const s4*)((const char*)buf + off);
}
__device__ __forceinline__ s4 load_x4(const void* data, size_t elemIdx, int isf32) {
    s4 r;
    if (isf32) {
        f4 v = *(const f4*)((const float*)data + elemIdx);
#pragma unroll
        for (int j = 0; j < 4; ++j) r[j] = (short)f2b(v[j]);
    } else {
        r = *(const s4*)((const u16*)data + elemIdx);
    }
    return r;
}

struct PackP {
    const void* src[10];
    const void* tps;
    int Kr[10], Nr[10], KS[10], sz[10];
};

__global__ __launch_bounds__(256) void repack_kernel(PackP p) {
    int gid = blockIdx.x * 256 + threadIdx.x;
    if (gid >= PACK_ELEMS) return;
    int isf32 = is_f32(p.tps);
    int idx = gid, m = 0, base = 0;
    while (m < 10 && idx >= p.sz[m]) { idx -= p.sz[m]; base += p.sz[m]; ++m; }
    if (m >= 10) return;
    int i = idx & 7;
    int l = (idx >> 3) & 63;
    int rest = idx >> 9;
    int ks = rest % p.KS[m];
    int nt = rest / p.KS[m];
    int k = ks * 32 + ((l >> 4) << 3) + i;
    int n = nt * 16 + (l & 15);
    u16 v = 0;
    if (k < p.Kr[m] && n < p.Nr[m]) v = f2b(rdany(p.src[m], k * p.Nr[m] + n, isf32));
    g_pack[base + idx] = v;
}

struct PrepP {
    const void *tps, *ob1, *ob2, *ub1, *ub2, *rb1, *rb2, *nb1, *nb2, *tb1, *tb2;
};

__global__ __launch_bounds__(256) void prep_bias(PrepP p) {
    int isf32 = is_f32(p.tps);
    int tid = threadIdx.x;
    for (int i = tid; i < 128; i += 256) {
        g_bias[OB1 + i] = (i < 100) ? rdany(p.ob1, i, isf32) : 0.f;
        g_bias[UB1 + i] = (i < 100) ? rdany(p.ub1, i, isf32) : 0.f;
        g_bias[RB1 + i] = (i < 100) ? rdany(p.rb1, i, isf32) : 0.f;
        g_bias[NB1 + i] = (i < 100) ? rdany(p.nb1, i, isf32) : 0.f;
        g_bias[TB1 + i] = (i < 100) ? rdany(p.tb1, i, isf32) : 0.f;
        g_bias[NB2 + i] = rdany(p.nb2, i, isf32);
        g_bias[TB2 + i] = rdany(p.tb2, i, isf32);
        g_bias[DTS + i] = (i == 0) ? -0.01f
                                   : (rdany(p.tps, 127 - i, isf32) - rdany(p.tps, 128 - i, isf32));
    }
    for (int i = tid; i < 64; i += 256) {
        g_bias[OB2 + i] = rdany(p.ob2, i, isf32);
        g_bias[UB2 + i] = rdany(p.ub2, i, isf32);
        g_bias[RB2 + i] = rdany(p.rb2, i, isf32);
    }
}

struct MainP {
    const void *data, *tps;
    void* out;
};

#define WLOAD(off, KSn, nt, ks) (*(const s8*)(pk + (off) + (((((nt) * (KSn)) + (ks)) << 6) + lane) * 8))
// TRANSPOSED: A = weight fragment, B = activation fragment -> C[ncol][traj]
#define MFMA(wf, af, c) __builtin_amdgcn_mfma_f32_16x16x32_bf16((wf), (af), (c), 0, 0, 0)

__global__ __launch_bounds__(512, 2) void enc_main(MainP p) {
    __shared__ u16 s_x[2][2048];   // [16][128] bf16 swizzled, double buffered
    __shared__ u16 s_yc[2048];     // [y | s]
    __shared__ u16 s_yc2[2048];    // [y_ode*r | s*r]
    __shared__ u16 s_hA[2048];     // h buffer (hode/hu/hns)
    __shared__ u16 s_hB[2048];     // hr
    __shared__ u16 s_us[1024];     // u gate, bf16 [16][64] swizzled
    __shared__ float s_b[NBIAS];

    int tid = threadIdx.x, lane = tid & 63, w = tid >> 6;   // w = 0..7
    int btraj = blockIdx.x << 4;
    const u16* pk = g_pack;
    int isf32 = is_f32(p.tps);

    for (int i = tid; i < NBIAS; i += 512) s_b[i] = g_bias[i];
    for (int i = tid; i < 2048; i += 512) s_yc[i] = 0;

    // persistent per-wave weight fragments (nt = w), ALL layers in registers
    s8 wl1u[8], wl1r[8], wl1n[8];
    s8 wod1[2];
    s8 wod2[4], w2x[4], wn2[4];
#pragma unroll
    for (int ks = 0; ks < 8; ++ks) {
        wl1u[ks] = WLOAD(OFF_UG1, 8, w, ks);
        wl1r[ks] = WLOAD(OFF_RG1, 8, w, ks);
        wl1n[ks] = WLOAD(OFF_NS1, 8, w, ks);
    }
    wod1[0] = WLOAD(OFF_OD1, 2, w, 0);
    wod1[1] = WLOAD(OFF_OD1, 2, w, 1);
#pragma unroll
    for (int ks = 0; ks < 4; ++ks) {
        wod2[ks] = WLOAD(OFF_OD2, 4, (w & 3), ks);
        wn2[ks] = WLOAD(OFF_NS2, 4, w, ks);
    }
    if (w < 4) {
#pragma unroll
        for (int ks = 0; ks < 4; ++ks) w2x[ks] = WLOAD(OFF_UG2, 4, w, ks);
    } else {
#pragma unroll
        for (int ks = 0; ks < 4; ++ks) w2x[ks] = WLOAD(OFF_RG2, 4, w - 4, ks);
    }

    f4 ymu_r = {0.f, 0.f, 0.f, 0.f};
    f4 s_r = {0.f, 0.f, 0.f, 0.f};
    f4 yo_r = {0.f, 0.f, 0.f, 0.f};
    f4 u_r = {0.f, 0.f, 0.f, 0.f};

    // x prefetch for step 0
    int xrow = tid >> 5, xk = tid & 31;
    int xoff = (xrow << 8) + ((xk << 3) ^ ((xrow & 7) << 4));
    {
        s4 xr = load_x4(p.data, ((size_t)(btraj + xrow) * TSTEPS + 127) * INPD + (xk << 2), isf32);
        *(s4*)((char*)s_x[0] + xoff) = xr;
    }
    __syncthreads();

    const f4 zero4 = {0.f, 0.f, 0.f, 0.f};
    int traj = lane & 15;
    int nbase = (w << 4) + ((lane >> 4) << 2);   // first of 4 owned output cols (0..127)

    // ---- prime: x fragments + u1/r1 x-partials for step 0 ----
    s8 axc0 = aread(s_x[0], lane, 0);
    s8 axc1 = aread(s_x[0], lane, 1);
    s8 axc2 = aread(s_x[0], lane, 2);
    s8 axc3 = aread(s_x[0], lane, 3);
    f4 auA = zero4, arA = zero4;    // u1/r1 partials: x (prev E/F or prime) + s (phase A)
    auA = MFMA(wl1u[4], axc0, auA);
    arA = MFMA(wl1r[4], axc0, arA);
    auA = MFMA(wl1u[5], axc1, auA);
    arA = MFMA(wl1r[5], axc1, arA);
    auA = MFMA(wl1u[6], axc2, auA);
    arA = MFMA(wl1r[6], axc2, arA);
    auA = MFMA(wl1u[7], axc3, auA);
    arA = MFMA(wl1r[7], axc3, arA);

    for (int it = 0; it < TSTEPS; ++it) {
        int cur = it & 1;
        float dt = s_b[DTS + it];

        s4 xnext;
        if (it < 127) {
            xnext = load_x4(p.data, ((size_t)(btraj + xrow) * TSTEPS + (126 - it)) * INPD + (xk << 2), isf32);
        }

        f4 an0 = zero4, an1 = zero4;

        // ---- Phase A: ode1 + u1/r1 s-partials (ks2,3) ----
        {
            s8 ay0 = aread(s_yc, lane, 0);
            s8 ay1 = aread(s_yc, lane, 1);
            s8 ay2 = aread(s_yc, lane, 2);
            s8 ay3 = aread(s_yc, lane, 3);
            f4 ao = zero4;
            ao = MFMA(wod1[0], ay0, ao);
            ao = MFMA(wod1[1], ay1, ao);
            auA = MFMA(wl1u[2], ay2, auA);
            arA = MFMA(wl1r[2], ay2, arA);
            auA = MFMA(wl1u[3], ay3, auA);
            arA = MFMA(wl1r[3], ay3, arA);
            f4 b4 = *(const f4*)(s_b + OB1 + nbase);
            hwrite4(s_hA, traj, nbase, tanh_(ao[0] + b4[0]), tanh_(ao[1] + b4[1]),
                    tanh_(ao[2] + b4[2]), tanh_(ao[3] + b4[3]));
        }
        __syncthreads();

        // ---- Phase B: ode2 (waves 0-3) / ns1 x-part (waves 4-7) ----
        if (w < 4) {
            f4 ac0 = zero4, ac1 = zero4;
            ac0 = MFMA(wod2[0], aread(s_hA, lane, 0), ac0);
            ac1 = MFMA(wod2[2], aread(s_hA, lane, 2), ac1);
            ac0 = MFMA(wod2[1], aread(s_hA, lane, 1), ac0);
            ac1 = MFMA(wod2[3], aread(s_hA, lane, 3), ac1);
            f4 b4 = *(const f4*)(s_b + OB2 + nbase);
#pragma unroll
            for (int j = 0; j < 4; ++j) yo_r[j] = ymu_r[j] + (ac0[j] + ac1[j] + b4[j]) * dt;
            hwrite4(s_yc, traj, nbase, yo_r[0], yo_r[1], yo_r[2], yo_r[3]);
        } else {
            an0 = MFMA(wl1n[4], axc0, an0);
            an1 = MFMA(wl1n[6], axc2, an1);
            an0 = MFMA(wl1n[5], axc1, an0);
            an1 = MFMA(wl1n[7], axc3, an1);
        }
        __syncthreads();

        // ---- Phase C: u1/r1 finish (y_ode ks0,1); store next x tile ----
        {
            s8 a0 = aread(s_yc, lane, 0);
            s8 a1 = aread(s_yc, lane, 1);
            f4 au1 = zero4, ar1 = zero4;
            au1 = MFMA(wl1u[0], a0, au1);
            ar1 = MFMA(wl1r[0], a0, ar1);
            au1 = MFMA(wl1u[1], a1, au1);
            ar1 = MFMA(wl1r[1], a1, ar1);
            if (it < 127) *(s4*)((char*)s_x[cur ^ 1] + xoff) = xnext;
            f4 bu4 = *(const f4*)(s_b + UB1 + nbase);
            f4 br4 = *(const f4*)(s_b + RB1 + nbase);
            hwrite4(s_hA, traj, nbase,
                    tanh_(auA[0] + au1[0] + bu4[0]), tanh_(auA[1] + au1[1] + bu4[1]),
                    tanh_(auA[2] + au1[2] + bu4[2]), tanh_(auA[3] + au1[3] + bu4[3]));
            hwrite4(s_hB, traj, nbase,
                    tanh_(arA[0] + ar1[0] + br4[0]), tanh_(arA[1] + ar1[1] + br4[1]),
                    tanh_(arA[2] + ar1[2] + br4[2]), tanh_(arA[3] + ar1[3] + br4[3]));
        }
        __syncthreads();

        // ---- Phase D: ns1 x-part+u2 (waves 0-3) / r2 + build yc2 (waves 4-7) ----
        if (w < 4) {
            an0 = MFMA(wl1n[4], axc0, an0);
            an1 = MFMA(wl1n[6], axc2, an1);
            an0 = MFMA(wl1n[5], axc1, an0);
            an1 = MFMA(wl1n[7], axc3, an1);
            f4 uac0 = zero4, uac1 = zero4;
            uac0 = MFMA(w2x[0], aread(s_hA, lane, 0), uac0);
            uac1 = MFMA(w2x[2], aread(s_hA, lane, 2), uac1);
            uac0 = MFMA(w2x[1], aread(s_hA, lane, 1), uac0);
            uac1 = MFMA(w2x[3], aread(s_hA, lane, 3), uac1);
            f4 b4 = *(const f4*)(s_b + UB2 + nbase);
#pragma unroll
            for (int j = 0; j < 4; ++j) u_r[j] = sigm(uac0[j] + uac1[j] + b4[j]);
            uwrite4(s_us, traj, nbase, u_r[0], u_r[1], u_r[2], u_r[3]);
        } else {
            f4 rac0 = zero4, rac1 = zero4;
            rac0 = MFMA(w2x[0], aread(s_hB, lane, 0), rac0);
            rac1 = MFMA(w2x[2], aread(s_hB, lane, 2), rac1);
            rac0 = MFMA(w2x[1], aread(s_hB, lane, 1), rac0);
            rac1 = MFMA(w2x[3], aread(s_hB, lane, 3), rac1);
            int sb = nbase - 64;
            f4 b4 = *(const f4*)(s_b + RB2 + sb);
            s4 yo4 = sread4(s_yc, traj, sb);   // y_ode (bf16, written in phase B)
            f4 rv;
#pragma unroll
            for (int j = 0; j < 4; ++j) rv[j] = sigm(rac0[j] + rac1[j] + b4[j]);
            hwrite4(s_yc2, traj, sb,
                    b2f((u16)yo4[0]) * rv[0], b2f((u16)yo4[1]) * rv[1],
                    b2f((u16)yo4[2]) * rv[2], b2f((u16)yo4[3]) * rv[3]);
            hwrite4(s_yc2, traj, nbase, s_r[0] * rv[0], s_r[1] * rv[1], s_r[2] * rv[2], s_r[3] * rv[3]);
        }
        __syncthreads();

        // ---- Phase E: ns1 finish (yc2 part) + next-x u/r partials (ks4,5) ----
        s8 axn0, axn1, axn2, axn3;
        f4 auN = zero4, arN = zero4;
        {
            an0 = MFMA(wl1n[0], aread(s_yc2, lane, 0), an0);
            an1 = MFMA(wl1n[2], aread(s_yc2, lane, 2), an1);
            an0 = MFMA(wl1n[1], aread(s_yc2, lane, 1), an0);
            an1 = MFMA(wl1n[3], aread(s_yc2, lane, 3), an1);
            if (it < 127) {
                axn0 = aread(s_x[cur ^ 1], lane, 0);
                axn1 = aread(s_x[cur ^ 1], lane, 1);
                auN = MFMA(wl1u[4], axn0, auN);
                arN = MFMA(wl1r[4], axn0, arN);
                auN = MFMA(wl1u[5], axn1, auN);
                arN = MFMA(wl1r[5], axn1, arN);
            }
            f4 b4 = *(const f4*)(s_b + NB1 + nbase);
            hwrite4(s_hA, traj, nbase,
                    tanh_(an0[0] + an1[0] + b4[0]), tanh_(an0[1] + an1[1] + b4[1]),
                    tanh_(an0[2] + an1[2] + b4[2]), tanh_(an0[3] + an1[3] + b4[3]));
        }
        __syncthreads();

        // ---- Phase F: ns2 + state update + next-x u/r partials (ks6,7) ----
        {
            f4 fn0 = zero4, fn1 = zero4;
            fn0 = MFMA(wn2[0], aread(s_hA, lane, 0), fn0);
            fn1 = MFMA(wn2[2], aread(s_hA, lane, 2), fn1);
            fn0 = MFMA(wn2[1], aread(s_hA, lane, 1), fn0);
            fn1 = MFMA(wn2[3], aread(s_hA, lane, 3), fn1);
            if (it < 127) {
                axn2 = aread(s_x[cur ^ 1], lane, 2);
                axn3 = aread(s_x[cur ^ 1], lane, 3);
                auN = MFMA(wl1u[6], axn2, auN);
                arN = MFMA(wl1r[6], axn2, arN);
                auN = MFMA(wl1u[7], axn3, auN);
                arN = MFMA(wl1r[7], axn3, arN);
            }

            f4 b4 = *(const f4*)(s_b + NB2 + nbase);
            if (w < 4) {
                s4 mm = sread4(s_x[cur], traj, 64 + nbase);
#pragma unroll
                for (int j = 0; j < 4; ++j) {
                    float nsv = fn0[j] + fn1[j] + b4[j];
                    float m = b2f((u16)mm[j]);
                    float mg = m * (1.f - u_r[j]);
                    ymu_r[j] = yo_r[j] + mg * (nsv - yo_r[j]);
                }
                hwrite4(s_yc, traj, nbase, ymu_r[0], ymu_r[1], ymu_r[2], ymu_r[3]);
            } else {
                int sb = nbase - 64;
                s4 mm = sread4(s_x[cur], traj, nbase);
                s4 uu = uread4(s_us, traj, sb);
#pragma unroll
                for (int j = 0; j < 4; ++j) {
                    float nsv = fabsf(fn0[j] + fn1[j] + b4[j]);
                    float m = b2f((u16)mm[j]);
                    float mg = m * (1.f - b2f((u16)uu[j]));
                    float nss = s_r[j] + mg * (nsv - s_r[j]);
                    s_r[j] = fabsf(nss);
                }
                hwrite4(s_yc, traj, nbase, s_r[0], s_r[1], s_r[2], s_r[3]);
            }
        }
        __syncthreads();

        // carry next-step x fragments and partials
        if (it < 127) {
            auA = auN;
            arA = arN;
            axc0 = axn0;
            axc1 = axn1;
            axc2 = axn2;
            axc3 = axn3;
        }
    }

    // ---- Final: z = mlp2([y|s], tz) ----
    s8 wt1[4], wt2[4];
#pragma unroll
    for (int ks = 0; ks < 4; ++ks) {
        wt1[ks] = WLOAD(OFF_TZ1, 4, w, ks);
        wt2[ks] = WLOAD(OFF_TZ2, 4, w, ks);
    }
    {
        f4 t1 = zero4;
#pragma unroll
        for (int ks = 0; ks < 4; ++ks) t1 = MFMA(wt1[ks], aread(s_yc, lane, ks), t1);
        f4 b4 = *(const f4*)(s_b + TB1 + nbase);
        hwrite4(s_hA, traj, nbase, tanh_(t1[0] + b4[0]), tanh_(t1[1] + b4[1]),
                tanh_(t1[2] + b4[2]), tanh_(t1[3] + b4[3]));
    }
    __syncthreads();
    {
        f4 t2 = zero4;
#pragma unroll
        for (int ks = 0; ks < 4; ++ks) t2 = MFMA(wt2[ks], aread(s_hA, lane, ks), t2);
        f4 b4 = *(const f4*)(s_b + TB2 + nbase);
        int gtraj = btraj + traj;
        f4 z;
        size_t base;
        if (w < 4) {
#pragma unroll
            for (int j = 0; j < 4; ++j) z[j] = t2[j] + b4[j];
            base = (size_t)gtraj * 64 + nbase;
        } else {
#pragma unroll
            for (int j = 0; j < 4; ++j) z[j] = fabsf(t2[j] + b4[j]);
            base = (size_t)N_TRAJ * 64 + (size_t)gtraj * 64 + (nbase - 64);
        }
        if (isf32) {
            *(f4*)((float*)p.out + base) = z;
        } else {
            uint2 pv;
            pv.x = cvtpk(z[0], z[1]);
            pv.y = cvtpk(z[2], z[3]);
            *(uint2*)((u16*)p.out + base) = pv;
        }
    }
}

extern "C" void kernel_launch(void* const* d_in, const int* in_sizes, int n_in,
                              void* d_out, int out_size, void* d_ws, size_t ws_size,
                              hipStream_t stream) {
    PackP pp;
    const int srcIdx[10] = {2, 6, 10, 14, 4, 8, 12, 16, 18, 20};
    const int Kr[10] = {256, 256, 256, 64, 100, 100, 100, 100, 128, 100};
    const int Nr[10] = {100, 100, 100, 100, 64, 64, 128, 64, 100, 128};
    const int KS[10] = {8, 8, 8, 2, 4, 4, 4, 4, 4, 4};
    const int NT[10] = {8, 8, 8, 8, 4, 4, 8, 4, 8, 8};
    for (int i = 0; i < 10; ++i) {
        pp.src[i] = d_in[srcIdx[i]];
        pp.Kr[i] = Kr[i];
        pp.Nr[i] = Nr[i];
        pp.KS[i] = KS[i];
        pp.sz[i] = KS[i] * NT[i] * 512;
    }
    pp.tps = d_in[1];
    repack_kernel<<<(PACK_ELEMS + 255) / 256, 256, 0, stream>>>(pp);

    PrepP bp;
    bp.tps = d_in[1];
    bp.ob1 = d_in[15]; bp.ob2 = d_in[17];
    bp.ub1 = d_in[3];  bp.ub2 = d_in[5];
    bp.rb1 = d_in[7];  bp.rb2 = d_in[9];
    bp.nb1 = d_in[11]; bp.nb2 = d_in[13];
    bp.tb1 = d_in[19]; bp.tb2 = d_in[21];
    prep_bias<<<1, 256, 0, stream>>>(bp);

    MainP mp;
    mp.data = d_in[0];
    mp.tps = d_in[1];
    mp.out = d_out;
    enc_main<<<N_TRAJ / 16, 512, 0, stream>>>(mp);
}